// Round 10
// baseline (363.988 us; speedup 1.0000x reference)
//
#include <hip/hip_runtime.h>
#include <hip/hip_bf16.h>
#include <hip/hip_fp16.h>
#include <stdint.h>

// B=16, N=2048, D=512. Inputs/outputs FLOAT32; internal bf16/fp16.
// Algebra: S = x(WqWk^T)x^T ; out*N = (c^T x)Wv  -> q,k,v never materialized.
#define NB 16
#define NN 2048
#define ND 512
#define SSCALE 0.044194173824159216f        // 1/sqrt(512)

typedef unsigned short u16;
typedef unsigned int u32;
typedef float f32x4 __attribute__((ext_vector_type(4)));
typedef __bf16 bf16x8 __attribute__((ext_vector_type(8)));
typedef unsigned short u16x8 __attribute__((ext_vector_type(8)));

__device__ __forceinline__ float bf2f(u16 h) {
  union { u32 u; float f; } v; v.u = ((u32)h) << 16; return v.f;
}
__device__ __forceinline__ u16 f2bf(float f) {
  union { float f; u32 u; } v; v.f = f;
  u32 r = v.u + 0x7fffu + ((v.u >> 16) & 1u);   // RNE
  return (u16)(r >> 16);
}
__device__ __forceinline__ u16 f2h(float f) {
  __half h = __float2half(f);
  union { __half h; u16 u; } v; v.h = h; return v.u;
}
__device__ __forceinline__ float h2f(u16 u) {
  union { u16 u; __half h; } v; v.u = u; return __half2float(v.h);
}

// async global->LDS, 16B/lane (wave-uniform base + lane*16 contract).
__device__ __forceinline__ void async16(const void* g, void* l) {
  __builtin_amdgcn_global_load_lds(
      (const __attribute__((address_space(1))) u32*)g,
      (__attribute__((address_space(3))) u32*)l,
      16, 0, 0);
}

#define TP 136   // LDS tile pitch (+8 halfs: de-conflict, keeps 16B align)

// ---------------------------------------------------------------------------
// C[m][n] = cscale * sum_k A[m][k] * B[n][k]   (B^T-input GEMM, 128x128 tile,
// BK=32, 4 waves 2x2, 4x4 of 16x16x32 bf16 MFMA). blockIdx.x=n-tile,
// .y=m-tile, .z=batch.
// MODE 0: C = bf16(C*cscale).
// MODE 1: C = fp16(exp(min(C*cscale,10))), atomicAdd row expsums to Lrow.
// Both modes stage the output tile in LDS and store coalesced (u16x8).
// AF32: A fp32 (convert to bf16 in regs while staging); else bf16 via async.
// ---------------------------------------------------------------------------
template <int MODE, bool AF32>
__global__ __launch_bounds__(256, 2) void gemm_bt(
    const void* __restrict__ Av, const u16* __restrict__ B, u16* __restrict__ C,
    float* __restrict__ Lrow, int lda, int ldb, int ldc, int K,
    long long sA, long long sB, long long sC, float cscale) {
  const int tid  = threadIdx.x;
  const int w    = tid >> 6;
  const int lane = tid & 63;
  const int wm   = w >> 1, wn = w & 1;
  const int lrow = lane & 15, quad = lane >> 4;
  const long long z = blockIdx.z;

  const float* Abf = (const float*)Av + z * sA + (size_t)blockIdx.y * 128 * lda;
  const u16*   Abh = (const u16*)Av   + z * sA + (size_t)blockIdx.y * 128 * lda;
  const u16*   Bb  = B + z * sB + (size_t)blockIdx.x * 128 * ldb;

  // Staging buffers (K-loop) and output tile (epilogue) share LDS.
  __shared__ __align__(16) union {
    struct { u16 a[128 * 32]; u16 b[128 * 32]; } st;
    u16 tile[128 * TP];
  } sm;

  f32x4 acc[4][4];
#pragma unroll
  for (int i = 0; i < 4; i++)
#pragma unroll
    for (int j = 0; j < 4; j++) acc[i][j] = (f32x4){0.f, 0.f, 0.f, 0.f};

  for (int k0 = 0; k0 < K; k0 += 32) {
    if (k0) __syncthreads();  // protect LDS before overwrite
    if (AF32) {
      u16x8 va[2];
#pragma unroll
      for (int t = 0; t < 2; t++) {
        int ch  = t * 256 + tid;      // 16B chunk id, 0..511
        int row = ch >> 2;
        int cc  = (ch & 3) * 8;
        const float4* p = (const float4*)(Abf + (size_t)row * lda + k0 + cc);
        float4 f0 = p[0], f1 = p[1];
        u16x8 r;
        r[0] = f2bf(f0.x); r[1] = f2bf(f0.y); r[2] = f2bf(f0.z); r[3] = f2bf(f0.w);
        r[4] = f2bf(f1.x); r[5] = f2bf(f1.y); r[6] = f2bf(f1.z); r[7] = f2bf(f1.w);
        va[t] = r;
        async16(Bb + (size_t)row * ldb + k0 + cc, &sm.st.b[ch * 8]);
      }
#pragma unroll
      for (int t = 0; t < 2; t++) *(u16x8*)&sm.st.a[(t * 256 + tid) * 8] = va[t];
    } else {
#pragma unroll
      for (int t = 0; t < 2; t++) {
        int ch  = t * 256 + tid;
        int row = ch >> 2;
        int cc  = (ch & 3) * 8;
        async16(Abh + (size_t)row * lda + k0 + cc, &sm.st.a[ch * 8]);
        async16(Bb  + (size_t)row * ldb + k0 + cc, &sm.st.b[ch * 8]);
      }
    }
    __syncthreads();  // drains vmcnt+lgkmcnt -> LDS ready

    bf16x8 af[4], bfr[4];
#pragma unroll
    for (int i = 0; i < 4; i++) {
      af[i]  = *(const bf16x8*)&sm.st.a[(wm * 64 + i * 16 + lrow) * 32 + quad * 8];
      bfr[i] = *(const bf16x8*)&sm.st.b[(wn * 64 + i * 16 + lrow) * 32 + quad * 8];
    }
#pragma unroll
    for (int i = 0; i < 4; i++)
#pragma unroll
      for (int j = 0; j < 4; j++)
        acc[i][j] =
            __builtin_amdgcn_mfma_f32_16x16x32_bf16(af[i], bfr[j], acc[i][j], 0, 0, 0);
  }

  __syncthreads();  // all waves done reading staging LDS; tile aliases it

  // Stage output tile in LDS. D col = lane&15, row = quad*4 + reg [m89/m91]
  if (MODE == 0) {
#pragma unroll
    for (int i = 0; i < 4; i++)
#pragma unroll
      for (int j = 0; j < 4; j++)
#pragma unroll
        for (int r = 0; r < 4; r++) {
          int row = wm * 64 + i * 16 + quad * 4 + r;
          int col = wn * 64 + j * 16 + lrow;
          sm.tile[row * TP + col] = f2bf(acc[i][j][r] * cscale);
        }
  } else {
    float* Lb = Lrow + z * NN + (size_t)blockIdx.y * 128;
#pragma unroll
    for (int i = 0; i < 4; i++)
#pragma unroll
      for (int r = 0; r < 4; r++) {
        int row = wm * 64 + i * 16 + quad * 4 + r;
        float rs = 0.f;
#pragma unroll
        for (int j = 0; j < 4; j++) {
          int col = wn * 64 + j * 16 + lrow;
          float e = __expf(fminf(acc[i][j][r] * cscale, 10.f));
          sm.tile[row * TP + col] = f2h(e);
          rs += e;
        }
        rs += __shfl_xor(rs, 1); rs += __shfl_xor(rs, 2);
        rs += __shfl_xor(rs, 4); rs += __shfl_xor(rs, 8);
        if (lrow == 0) atomicAdd(&Lb[row], rs);
      }
  }
  __syncthreads();

  // Coalesced store: 8 steps x (u16x8 per thread); 16 rows / step.
  u16* Cb = C + z * sC + (size_t)blockIdx.y * 128 * ldc + (size_t)blockIdx.x * 128;
#pragma unroll
  for (int s = 0; s < 8; s++) {
    int flat = s * 2048 + tid * 8;
    int row = flat >> 7, col = flat & 127;
    *(u16x8*)(Cb + (size_t)row * ldc + col) = *(const u16x8*)&sm.tile[row * TP + col];
  }
}

// ---------------------------------------------------------------------------
// fp32 -> bf16 plain cast, 8 elements/thread
// ---------------------------------------------------------------------------
__global__ void cast_f32_bf16(const float* __restrict__ x, u16* __restrict__ xb) {
  size_t i = ((size_t)blockIdx.x * 256 + threadIdx.x) * 8;
  float4 f0 = *(const float4*)(x + i);
  float4 f1 = *(const float4*)(x + i + 4);
  u16x8 r;
  r[0] = f2bf(f0.x); r[1] = f2bf(f0.y); r[2] = f2bf(f0.z); r[3] = f2bf(f0.w);
  r[4] = f2bf(f1.x); r[5] = f2bf(f1.y); r[6] = f2bf(f1.z); r[7] = f2bf(f1.w);
  *(u16x8*)(xb + i) = r;
}

// ---------------------------------------------------------------------------
// c[z*NN+m] += sum_n E[z][n0+n][m] / L[z*NN+n0+n]     (E already exp'ed)
// grid (1, 16 n-chunks of 128, CH batches), 256 thr, 8 cols/thread (16B loads)
// ---------------------------------------------------------------------------
__global__ void col_sum(const __half* __restrict__ E, const float* __restrict__ L,
                        float* __restrict__ c) {
  int m8 = threadIdx.x * 8;
  int n0 = blockIdx.y * 128;
  int z  = blockIdx.z;
  const u16* Ep = (const u16*)E + ((size_t)z * NN + n0) * NN + m8;
  const float* lp = L + (size_t)z * NN + n0;
  float a[8];
#pragma unroll
  for (int k = 0; k < 8; k++) a[k] = 0.f;
#pragma unroll 2
  for (int n = 0; n < 128; n++) {
    u16x8 h = *(const u16x8*)(Ep + (size_t)n * NN);
    float il = 1.0f / lp[n];
#pragma unroll
    for (int k = 0; k < 8; k++) a[k] += h2f(h[k]) * il;
  }
  float* cp = c + (size_t)z * NN + m8;
#pragma unroll
  for (int k = 0; k < 8; k++) atomicAdd(&cp[k], a[k]);
}

// ---------------------------------------------------------------------------
// t[b][d] += sum_m c[b][m] * xb[b][m][d]
// grid (B batches, 16 m-chunks of 128), 256 thr (2 d-cols each), coalesced.
// ---------------------------------------------------------------------------
__global__ void tx_accum(const u16* __restrict__ xb, const float* __restrict__ c,
                         float* __restrict__ t) {
  int b = blockIdx.x, mc = blockIdx.y, d = threadIdx.x;
  const u16* vp = xb + ((size_t)b * NN + mc * 128) * ND;
  const float* cp = c + b * NN + mc * 128;
  float a0 = 0.f, a1 = 0.f;
#pragma unroll 4
  for (int m = 0; m < 128; m++) {
    float cm = cp[m];
    a0 += cm * bf2f(vp[(size_t)m * ND + d]);
    a1 += cm * bf2f(vp[(size_t)m * ND + 256 + d]);
  }
  atomicAdd(&t[b * ND + d], a0);
  atomicAdd(&t[b * ND + 256 + d], a1);
}

// ---------------------------------------------------------------------------
// out[b][d] = (1/NN) * sum_l t[b][l] * Wv[l][d]   (Wv fp32, full precision)
// ---------------------------------------------------------------------------
__global__ void final_wv(const float* __restrict__ t, const float* __restrict__ Wv,
                         float* __restrict__ out) {
  int b = blockIdx.x, d = blockIdx.y * 256 + threadIdx.x;
  const float* tb = t + b * ND;
  float a = 0.f;
#pragma unroll 4
  for (int l = 0; l < ND; l++) a += tb[l] * Wv[(size_t)l * ND + d];
  out[b * ND + d] = a * (1.f / (float)NN);
}

// ---------------------------------------------------------------------------
extern "C" void kernel_launch(void* const* d_in, const int* in_sizes, int n_in,
                              void* d_out, int out_size, void* d_ws, size_t ws_size,
                              hipStream_t stream) {
  const float* x  = (const float*)d_in[0];  // [16,2048,512] fp32
  const float* Wk = (const float*)d_in[1];  // [512,512]     fp32
  const float* Wq = (const float*)d_in[2];  // [512,512]     fp32
  const float* Wv = (const float*)d_in[3];  // [512,512]     fp32
  float* out = (float*)d_out;               // [16,512]      fp32

  // --- small fixed region (~1.3 MB). L,c,t contiguous (one memset). ---
  char* ws = (char*)d_ws;
  size_t off = 0;
  float* L   = (float*)(ws + off); off += (size_t)NB * NN * 4;     // 128 KB
  float* c   = (float*)(ws + off); off += (size_t)NB * NN * 4;     // 128 KB
  float* t   = (float*)(ws + off); off += (size_t)NB * ND * 4;     // 32 KB
  u16* Wqb   = (u16*)(ws + off);   off += (size_t)ND * ND * 2;     // 512 KB
  u16* Mt    = (u16*)(ws + off);   off += (size_t)ND * ND * 2;     // 512 KB
  const size_t small_total = off;

  // --- big region: xb (33.6) + y (33.6) + E chunk (adaptive) ---
  const size_t XBSZ = (size_t)NB * NN * ND * 2;   // 33.55 MB
  const size_t SB1  = (size_t)NN * NN * 2;        // 8.39 MB / batch of E
  u16* xb   = (u16*)(ws + small_total);
  u16* y    = (u16*)(ws + small_total + XBSZ);
  __half* E = (__half*)(ws + small_total + 2 * XBSZ);
  size_t srem = ws_size > small_total + 2 * XBSZ
              ? ws_size - small_total - 2 * XBSZ : 0;
  int chb = 0, sr = 128;
  if      (srem >= 16 * SB1) chb = 16;
  else if (srem >=  8 * SB1) chb = 8;
  else if (srem >=  4 * SB1) chb = 4;
  else if (srem >=  2 * SB1) chb = 2;
  else if (srem >=  1 * SB1) chb = 1;
  else {
    if      (srem >= (size_t)1024 * NN * 2) sr = 1024;
    else if (srem >= (size_t)512  * NN * 2) sr = 512;
    else if (srem >= (size_t)256  * NN * 2) sr = 256;
  }

  // L, c, t are contiguous: single memset (ws is 0xAA-poisoned each call).
  (void)hipMemsetAsync(L, 0, (size_t)(2 * NB * NN + NB * ND) * sizeof(float),
                       stream);

  // xb = bf16(x); Wqb = bf16(Wq)
  cast_f32_bf16<<<8192, 256, 0, stream>>>(x, xb);
  cast_f32_bf16<<<128, 256, 0, stream>>>(Wq, Wqb);

  // Mt[n][k] = SSCALE * sum_l Wk[n][l]*Wq[k][l]  (= (Wq Wk^T)^T * scale)
  gemm_bt<0, true><<<dim3(4, 4, 1), 256, 0, stream>>>(
      Wk, Wqb, Mt, nullptr, ND, ND, ND, ND, 0, 0, 0, SSCALE);

  // y = x * M   (M=32768, N=512, K=512)  -> bf16 [B*N, 512]
  gemm_bt<0, false><<<dim3(4, 256, 1), 256, 0, stream>>>(
      xb, Mt, y, nullptr, ND, ND, ND, ND, 0, 0, 0, 1.0f);

  const long long sR = (long long)NN * ND;   // per-batch row stride (y, xb)
  const long long sS = (long long)NN * NN;

  if (chb >= 1) {
    for (int cc = 0; cc < NB / chb; ++cc) {
      size_t o = (size_t)cc * chb * NN;
      // E = exp(y_b * xb_b^T), row sums into L
      gemm_bt<1, false><<<dim3(16, 16, chb), 256, 0, stream>>>(
          y + o * ND, xb + o * ND, (u16*)E, L + o, ND, ND, NN, ND,
          sR, sR, sS, 1.0f);
      col_sum<<<dim3(1, 16, chb), 256, 0, stream>>>(E, L + o, c + o);
    }
  } else {  // sub-batch chunks of sr rows
    for (int b = 0; b < NB; ++b) {
      for (int ch = 0; ch < NN / sr; ++ch) {
        size_t o = (size_t)b * NN + (size_t)ch * sr;
        gemm_bt<1, false><<<dim3(16, sr / 128, 1), 256, 0, stream>>>(
            y + o * ND, xb + (size_t)b * NN * ND, (u16*)E, L + o,
            ND, ND, NN, ND, 0, 0, 0, 1.0f);
        col_sum<<<dim3(1, sr / 128, 1), 256, 0, stream>>>(E, L + o, c + b * NN);
      }
    }
  }

  // t[b] = c_b^T x_b ;  out = (t * Wv) / NN
  tx_accum<<<dim3(NB, 16), 256, 0, stream>>>(xb, c, t);
  final_wv<<<dim3(NB, 2), 256, 0, stream>>>(t, Wv, out);
  (void)in_sizes; (void)n_in; (void)out_size;
}